// Round 15
// baseline (74.379 us; speedup 1.0000x reference)
//
#include <hip/hip_runtime.h>

#define NB   8
#define ND   64
#define NP   1024
#define KDIM 128
#define HID  256
#define OUTD 256
#define CSC  2.885390081777927f   // 2*log2(e)

typedef __attribute__((ext_vector_type(8))) short  bf16x8;
typedef __attribute__((ext_vector_type(4))) float  f32x4;

// E-trick: E = exp2(CSC*proj) = e^{2*proj};
// sigma = 1/(1+Ed*Ep) = rcp(fma(Ed,Ep,1));  tanh = 1 - 2*sigma.
// EhpT transposed [b][h][j]. Projection on MFMA bf16. scores+softmax+facc
// fused per (b,i) row. R15: b = blk&7 -> XCD-affine batches (blocks round-
// robin XCDs, m09) so each XCD's L2 holds only its b's 2MB slice (R14 FETCH
// was 66MB = 8 XCDs x 8MB re-fetch); 1024-thr blocks -> 32 waves/CU cap.

__device__ __forceinline__ ushort f2bf(float f) {
    unsigned u = __float_as_uint(f);
    return (ushort)((u + 0x7FFFu + ((u >> 16) & 1u)) >> 16);
}

// K0: cast X -> bf16 (k-contig); W -> bf16 TRANSPOSED (WT[n][k]).
__global__ __launch_bounds__(256) void k_cast(
    const float* __restrict__ Xd, const float* __restrict__ Xp,
    const float* __restrict__ Wd, const float* __restrict__ Wa,
    const float* __restrict__ Wp, const float* __restrict__ Wb,
    ushort* __restrict__ Xdbf, ushort* __restrict__ Xpbf,
    ushort* __restrict__ WdT, ushort* __restrict__ WaT,
    ushort* __restrict__ WpT, ushort* __restrict__ WbT) {
    int blk = blockIdx.x, t = threadIdx.x;
    if (blk < 1024) {
        size_t i = ((size_t)blk << 10) + ((size_t)t << 2);
        float4 v = *(const float4*)(Xp + i);
        ushort4 o; o.x = f2bf(v.x); o.y = f2bf(v.y); o.z = f2bf(v.z); o.w = f2bf(v.w);
        *(ushort4*)(Xpbf + i) = o;
    } else if (blk < 1088) {
        size_t i = ((size_t)(blk - 1024) << 10) + ((size_t)t << 2);
        float4 v = *(const float4*)(Xd + i);
        ushort4 o; o.x = f2bf(v.x); o.y = f2bf(v.y); o.z = f2bf(v.z); o.w = f2bf(v.w);
        *(ushort4*)(Xdbf + i) = o;
    } else {
        int r = blk - 1088, mat = r >> 5;
        const float* W = (mat == 0) ? Wd : (mat == 1) ? Wa : (mat == 2) ? Wp : Wb;
        ushort* WT = (mat == 0) ? WdT : (mat == 1) ? WaT : (mat == 2) ? WpT : WbT;
        int o0 = ((r & 31) << 10) + (t << 2);
        int n = o0 >> 7, k0 = o0 & 127;
        ushort4 o;
        o.x = f2bf(W[(k0 + 0) * HID + n]);
        o.y = f2bf(W[(k0 + 1) * HID + n]);
        o.z = f2bf(W[(k0 + 2) * HID + n]);
        o.w = f2bf(W[(k0 + 3) * HID + n]);
        *(ushort4*)(WT + o0) = o;
    }
}

// K1: MFMA projection + fused exp2 (verified absmax 0.0625).
__global__ __launch_bounds__(256) void k_proj_mfma(
    const ushort* __restrict__ Xpbf, const ushort* __restrict__ Xdbf,
    const ushort* __restrict__ WdT, const ushort* __restrict__ WaT,
    const ushort* __restrict__ WpT, const ushort* __restrict__ WbT,
    float* __restrict__ Ehd, float* __restrict__ Efd,
    float* __restrict__ EhpT, float* __restrict__ Efp) {
    int blk = blockIdx.x, t = threadIdx.x;
    const ushort *A, *B;
    float* out; size_t obase; int ostride, am0, bn0;
    if (blk < 512) {
        int mt = blk >> 2, nt = blk & 3;
        A = Xpbf; am0 = mt * 64; B = WbT; bn0 = nt * 64;
        out = Efp; obase = (size_t)am0 * HID + bn0; ostride = HID;
    } else if (blk < 1024) {
        int r = blk - 512, b = r >> 6, rr = r & 63;
        int mt = rr >> 4, nt = rr & 15;
        A = WpT; am0 = mt * 64;
        B = Xpbf + (size_t)b * NP * KDIM; bn0 = nt * 64;
        out = EhpT; obase = ((size_t)(b * 256 + am0)) * NP + bn0; ostride = NP;
    } else if (blk < 1056) {
        int r = blk - 1024; int mt = r >> 2, nt = r & 3;
        A = Xdbf; am0 = mt * 64; B = WdT; bn0 = nt * 64;
        out = Ehd; obase = (size_t)am0 * HID + bn0; ostride = HID;
    } else {
        int r = blk - 1056; int mt = r >> 2, nt = r & 3;
        A = Xdbf; am0 = mt * 64; B = WaT; bn0 = nt * 64;
        out = Efd; obase = (size_t)am0 * HID + bn0; ostride = HID;
    }
    int l = t & 63, w = t >> 6;
    int wm = (w >> 1) << 5, wn = (w & 1) << 5;
    int lr = l & 15, lk = (l >> 4) << 3;
    const ushort* Ab = A + (size_t)(am0 + wm + lr) * KDIM + lk;
    const ushort* Bb = B + (size_t)(bn0 + wn + lr) * KDIM + lk;

    bf16x8 af[2][4], bfr[2][4];
#pragma unroll
    for (int f = 0; f < 2; ++f)
#pragma unroll
        for (int ks = 0; ks < 4; ++ks) {
            af[f][ks]  = *(const bf16x8*)(Ab + (size_t)(f << 4) * KDIM + (ks << 5));
            bfr[f][ks] = *(const bf16x8*)(Bb + (size_t)(f << 4) * KDIM + (ks << 5));
        }

    f32x4 acc[2][2];
#pragma unroll
    for (int mf = 0; mf < 2; ++mf)
#pragma unroll
        for (int nf = 0; nf < 2; ++nf) acc[mf][nf] = (f32x4){0.f, 0.f, 0.f, 0.f};
#pragma unroll
    for (int ks = 0; ks < 4; ++ks)
#pragma unroll
        for (int mf = 0; mf < 2; ++mf)
#pragma unroll
            for (int nf = 0; nf < 2; ++nf)
                acc[mf][nf] = __builtin_amdgcn_mfma_f32_16x16x32_bf16(
                    af[mf][ks], bfr[nf][ks], acc[mf][nf], 0, 0, 0);

#pragma unroll
    for (int mf = 0; mf < 2; ++mf)
#pragma unroll
        for (int nf = 0; nf < 2; ++nf)
#pragma unroll
            for (int r = 0; r < 4; ++r) {
                int m = wm + (mf << 4) + ((l >> 4) << 2) + r;
                int n = wn + (nf << 4) + (l & 15);
                out[obase + (size_t)m * ostride + n] =
                    __builtin_amdgcn_exp2f(acc[mf][nf][r] * CSC);
            }
}

// K2: FUSED scores+softmax+facc. One block per (b,i) row, 1024 threads.
// b = blk&7 -> XCD-affine (each XCD's L2 caches only one b's EhpT+Efp).
// Phase1: j = t (1/thread), coalesced EhpT. Phase2: exp2 + block sum -> A2
// in LDS. Phase3: o = t&255, j-quarter = t>>8 (256 j each) + 4-way red.
__global__ __launch_bounds__(1024) void k_fused(
    const float* __restrict__ Ehd, const float* __restrict__ EhpT,
    const float* __restrict__ Efd, const float* __restrict__ Efp,
    const float* __restrict__ wsc, float* __restrict__ part) {
    int blk = blockIdx.x;
    int b = blk & 7, i = blk >> 3;   // XCD-affine batch
    int row = b * ND + i;
    int t = threadIdx.x;
    __shared__ float4 hs4[64];       // Ehd row, 1 KB
    __shared__ float4 w24[64];       // -2*w, 1 KB
    __shared__ float4 a2v[256];      // A2, 4 KB
    __shared__ float  red[1024];     // 4 KB
    __shared__ float  wsum[16];
    if (t < 64) {
        hs4[t] = ((const float4*)(Ehd + ((size_t)row << 8)))[t];
        float4 wv = ((const float4*)wsc)[t];
        w24[t] = make_float4(-2.f * wv.x, -2.f * wv.y, -2.f * wv.z, -2.f * wv.w);
    }
    __syncthreads();

    // ---- phase 1: shifted score for j = t ----
    const float* pT = EhpT + ((size_t)(b << 8)) * NP + t;
    float acc0 = 0.f;
    for (int h4 = 0; h4 < 64; ++h4) {
        float4 hv = hs4[h4];                 // LDS broadcast
        float4 wv = w24[h4];
        const float* pb = pT + (size_t)(h4 << 2) * NP;
        float p0 = pb[0];
        float p1 = pb[NP];
        float p2 = pb[2 * NP];
        float p3 = pb[3 * NP];
        acc0 = fmaf(wv.x, __builtin_amdgcn_rcpf(fmaf(hv.x, p0, 1.f)), acc0);
        acc0 = fmaf(wv.y, __builtin_amdgcn_rcpf(fmaf(hv.y, p1, 1.f)), acc0);
        acc0 = fmaf(wv.z, __builtin_amdgcn_rcpf(fmaf(hv.z, p2, 1.f)), acc0);
        acc0 = fmaf(wv.w, __builtin_amdgcn_rcpf(fmaf(hv.w, p3, 1.f)), acc0);
    }

    // ---- phase 2: softmax (no max pass: |S| <= 2*sum|w| ~ 32, fp32-safe) ----
    const float L2E = 1.4426950408889634f;
    float e0 = __builtin_amdgcn_exp2f(acc0 * L2E);
    float s4 = e0;
#pragma unroll
    for (int off = 32; off > 0; off >>= 1) s4 += __shfl_xor(s4, off, 64);
    if ((t & 63) == 0) wsum[t >> 6] = s4;
    __syncthreads();
    float tot = (((wsum[0] + wsum[1]) + (wsum[2] + wsum[3])) +
                 ((wsum[4] + wsum[5]) + (wsum[6] + wsum[7]))) +
                (((wsum[8] + wsum[9]) + (wsum[10] + wsum[11])) +
                 ((wsum[12] + wsum[13]) + (wsum[14] + wsum[15])));
    float sneg = -2.0f * __builtin_amdgcn_rcpf(tot);   // A2 = -2*A
    ((float*)a2v)[t] = e0 * sneg;
    __syncthreads();

    // ---- phase 3: facc. o = t&255, j-quarter = t>>8 (256 j each) ----
    int o = t & 255, q = t >> 8;
    float fdv = Efd[((size_t)row << 8) + o];
    const float* fp = Efp + (((size_t)(b * NP + (q << 8))) << 8) + o;
    const float4* ah = a2v + (q << 6);       // 64 float4 = 256 floats
    float accA = 0.f, accB = 0.f;
    for (int j4 = 0; j4 < 64; ++j4) {
        const float* fj = fp + ((size_t)j4 << 10);
        float f0 = fj[0];
        float f1 = fj[256];
        float f2 = fj[512];
        float f3 = fj[768];
        float4 av = ah[j4];
        accA = fmaf(av.x, __builtin_amdgcn_rcpf(fmaf(fdv, f0, 1.f)), accA);
        accB = fmaf(av.y, __builtin_amdgcn_rcpf(fmaf(fdv, f1, 1.f)), accB);
        accA = fmaf(av.z, __builtin_amdgcn_rcpf(fmaf(fdv, f2, 1.f)), accA);
        accB = fmaf(av.w, __builtin_amdgcn_rcpf(fmaf(fdv, f3, 1.f)), accB);
    }
    red[t] = accA + accB;
    __syncthreads();
    if (t < 256)
        part[((size_t)blk << 8) + t] =
            (red[t] + red[t + 256]) + (red[t + 512] + red[t + 768]);
}

// K3: out[b][o] = 64 + sum over 64 i-rows. grid = 8, 256 threads.
// part is indexed by blk = i*8 + b (fused grid order), so stride 8.
__global__ __launch_bounds__(256) void k_reduce(
    const float* __restrict__ part, float* __restrict__ out) {
    int b = blockIdx.x, t = threadIdx.x;
    float s = 64.0f;   // sum_i sum_j A_ij * 1
#pragma unroll 8
    for (int i = 0; i < 64; ++i)
        s += part[((size_t)(i * 8 + b) << 8) + t];
    out[(b << 8) + t] = s;
}

extern "C" void kernel_launch(void* const* d_in, const int* in_sizes, int n_in,
                              void* d_out, int out_size, void* d_ws, size_t ws_size,
                              hipStream_t stream) {
    const float* Xd  = (const float*)d_in[0];
    const float* Xp  = (const float*)d_in[1];
    const float* Wd  = (const float*)d_in[2];
    const float* Wp  = (const float*)d_in[3];
    const float* Wa  = (const float*)d_in[4];
    const float* Wb  = (const float*)d_in[5];
    const float* wsc = (const float*)d_in[6];
    float* out = (float*)d_out;

    float* ws = (float*)d_ws;
    float* Ehd  = ws;                       // 131072 f
    float* Efd  = Ehd + NB * ND * HID;      // 131072 f
    float* EhpT = Efd + NB * ND * OUTD;     // 2097152 f  ([b][h][j])
    float* Efp  = EhpT + NB * NP * HID;     // 2097152 f
    float* stage = Efp + NB * NP * OUTD;    // staging region (bf16)
    ushort* Xpbf = (ushort*)stage;          // 1048576 us = 2 MB
    ushort* Xdbf = Xpbf + NB * NP * KDIM;   // 65536 us
    ushort* WdT  = Xdbf + 65536;            // 32768 us each
    ushort* WaT  = WdT + 32768;
    ushort* WpT  = WaT + 32768;
    ushort* WbT  = WpT + 32768;
    float* part  = stage;                   // overlay: stage dead after k_proj_mfma

    k_cast     <<<1216, 256, 0, stream>>>(Xd, Xp, Wd, Wa, Wp, Wb,
                                          Xdbf, Xpbf, WdT, WaT, WpT, WbT);
    k_proj_mfma<<<1088, 256, 0, stream>>>(Xpbf, Xdbf, WdT, WaT, WpT, WbT,
                                          Ehd, Efd, EhpT, Efp);
    k_fused    <<<NB * ND, 1024, 0, stream>>>(Ehd, EhpT, Efd, Efp, wsc, part);
    k_reduce   <<<NB, 256, 0, stream>>>(part, out);
}

// Round 16
// 65.699 us; speedup vs baseline: 1.1321x; 1.1321x over previous
//
#include <hip/hip_runtime.h>

#define NB   8
#define ND   64
#define NP   1024
#define KDIM 128
#define HID  256
#define OUTD 256
#define CSC  2.885390081777927f   // 2*log2(e)

typedef __attribute__((ext_vector_type(8))) short  bf16x8;
typedef __attribute__((ext_vector_type(4))) float  f32x4;

// E-trick: sigma = rcp(fma(Ed,Ep,1)); tanh = 1-2*sigma. EhpT transposed.
// R16: k_fused was L1-BW-bound (2MB/block through 64B/cy = 27us > 20.5us
// VALU floor; R15's occupancy/FETCH fixes were neutral). Fix: 2 i-rows per
// block -> every EhpT/Efp byte feeds 2 sigma chains; float4 loads 8 evals/ld.

__device__ __forceinline__ ushort f2bf(float f) {
    unsigned u = __float_as_uint(f);
    return (ushort)((u + 0x7FFFu + ((u >> 16) & 1u)) >> 16);
}

// K0: cast X -> bf16 (k-contig); W -> bf16 TRANSPOSED (WT[n][k]).
__global__ __launch_bounds__(256) void k_cast(
    const float* __restrict__ Xd, const float* __restrict__ Xp,
    const float* __restrict__ Wd, const float* __restrict__ Wa,
    const float* __restrict__ Wp, const float* __restrict__ Wb,
    ushort* __restrict__ Xdbf, ushort* __restrict__ Xpbf,
    ushort* __restrict__ WdT, ushort* __restrict__ WaT,
    ushort* __restrict__ WpT, ushort* __restrict__ WbT) {
    int blk = blockIdx.x, t = threadIdx.x;
    if (blk < 1024) {
        size_t i = ((size_t)blk << 10) + ((size_t)t << 2);
        float4 v = *(const float4*)(Xp + i);
        ushort4 o; o.x = f2bf(v.x); o.y = f2bf(v.y); o.z = f2bf(v.z); o.w = f2bf(v.w);
        *(ushort4*)(Xpbf + i) = o;
    } else if (blk < 1088) {
        size_t i = ((size_t)(blk - 1024) << 10) + ((size_t)t << 2);
        float4 v = *(const float4*)(Xd + i);
        ushort4 o; o.x = f2bf(v.x); o.y = f2bf(v.y); o.z = f2bf(v.z); o.w = f2bf(v.w);
        *(ushort4*)(Xdbf + i) = o;
    } else {
        int r = blk - 1088, mat = r >> 5;
        const float* W = (mat == 0) ? Wd : (mat == 1) ? Wa : (mat == 2) ? Wp : Wb;
        ushort* WT = (mat == 0) ? WdT : (mat == 1) ? WaT : (mat == 2) ? WpT : WbT;
        int o0 = ((r & 31) << 10) + (t << 2);
        int n = o0 >> 7, k0 = o0 & 127;
        ushort4 o;
        o.x = f2bf(W[(k0 + 0) * HID + n]);
        o.y = f2bf(W[(k0 + 1) * HID + n]);
        o.z = f2bf(W[(k0 + 2) * HID + n]);
        o.w = f2bf(W[(k0 + 3) * HID + n]);
        *(ushort4*)(WT + o0) = o;
    }
}

// K1: MFMA projection + fused exp2 (verified absmax 0.0625).
__global__ __launch_bounds__(256) void k_proj_mfma(
    const ushort* __restrict__ Xpbf, const ushort* __restrict__ Xdbf,
    const ushort* __restrict__ WdT, const ushort* __restrict__ WaT,
    const ushort* __restrict__ WpT, const ushort* __restrict__ WbT,
    float* __restrict__ Ehd, float* __restrict__ Efd,
    float* __restrict__ EhpT, float* __restrict__ Efp) {
    int blk = blockIdx.x, t = threadIdx.x;
    const ushort *A, *B;
    float* out; size_t obase; int ostride, am0, bn0;
    if (blk < 512) {
        int mt = blk >> 2, nt = blk & 3;
        A = Xpbf; am0 = mt * 64; B = WbT; bn0 = nt * 64;
        out = Efp; obase = (size_t)am0 * HID + bn0; ostride = HID;
    } else if (blk < 1024) {
        int r = blk - 512, b = r >> 6, rr = r & 63;
        int mt = rr >> 4, nt = rr & 15;
        A = WpT; am0 = mt * 64;
        B = Xpbf + (size_t)b * NP * KDIM; bn0 = nt * 64;
        out = EhpT; obase = ((size_t)(b * 256 + am0)) * NP + bn0; ostride = NP;
    } else if (blk < 1056) {
        int r = blk - 1024; int mt = r >> 2, nt = r & 3;
        A = Xdbf; am0 = mt * 64; B = WdT; bn0 = nt * 64;
        out = Ehd; obase = (size_t)am0 * HID + bn0; ostride = HID;
    } else {
        int r = blk - 1056; int mt = r >> 2, nt = r & 3;
        A = Xdbf; am0 = mt * 64; B = WaT; bn0 = nt * 64;
        out = Efd; obase = (size_t)am0 * HID + bn0; ostride = HID;
    }
    int l = t & 63, w = t >> 6;
    int wm = (w >> 1) << 5, wn = (w & 1) << 5;
    int lr = l & 15, lk = (l >> 4) << 3;
    const ushort* Ab = A + (size_t)(am0 + wm + lr) * KDIM + lk;
    const ushort* Bb = B + (size_t)(bn0 + wn + lr) * KDIM + lk;

    bf16x8 af[2][4], bfr[2][4];
#pragma unroll
    for (int f = 0; f < 2; ++f)
#pragma unroll
        for (int ks = 0; ks < 4; ++ks) {
            af[f][ks]  = *(const bf16x8*)(Ab + (size_t)(f << 4) * KDIM + (ks << 5));
            bfr[f][ks] = *(const bf16x8*)(Bb + (size_t)(f << 4) * KDIM + (ks << 5));
        }

    f32x4 acc[2][2];
#pragma unroll
    for (int mf = 0; mf < 2; ++mf)
#pragma unroll
        for (int nf = 0; nf < 2; ++nf) acc[mf][nf] = (f32x4){0.f, 0.f, 0.f, 0.f};
#pragma unroll
    for (int ks = 0; ks < 4; ++ks)
#pragma unroll
        for (int mf = 0; mf < 2; ++mf)
#pragma unroll
            for (int nf = 0; nf < 2; ++nf)
                acc[mf][nf] = __builtin_amdgcn_mfma_f32_16x16x32_bf16(
                    af[mf][ks], bfr[nf][ks], acc[mf][nf], 0, 0, 0);

#pragma unroll
    for (int mf = 0; mf < 2; ++mf)
#pragma unroll
        for (int nf = 0; nf < 2; ++nf)
#pragma unroll
            for (int r = 0; r < 4; ++r) {
                int m = wm + (mf << 4) + ((l >> 4) << 2) + r;
                int n = wn + (nf << 4) + (l & 15);
                out[obase + (size_t)m * ostride + n] =
                    __builtin_amdgcn_exp2f(acc[mf][nf][r] * CSC);
            }
}

// K2: FUSED scores+softmax+facc, 2 i-rows per block. grid = 256 (1/CU),
// 1024 threads. b = blk&7 XCD-affine.
// P1: thread = (jq=t&255 -> 4 j, hq=t>>8 -> 64 h); float4 EhpT load feeds
//     8 evals (4 j x 2 rows). Partials -> 8 LDS planes, reduce over 4 hq.
// P2: thread t owns j=t for both rows: exp2 + per-row block sum -> A2 LDS.
// P3: thread = (oq=t&63 -> 4 o, jg=t>>6 -> 64 j); float4 Efp load feeds
//     8 evals. Partials -> 8 planes, reduce over 16 jg -> part.
__global__ __launch_bounds__(1024) void k_fused(
    const float* __restrict__ Ehd, const float* __restrict__ EhpT,
    const float* __restrict__ Efd, const float* __restrict__ Efp,
    const float* __restrict__ wsc, float* __restrict__ part) {
    int blk = blockIdx.x;
    int b = blk & 7, pair = blk >> 3;
    int row0 = b * ND + pair * 2;        // rows row0, row0+1
    int t = threadIdx.x;

    __shared__ float2 hrow[256];         // (Ehd r0, Ehd r1)  2 KB
    __shared__ float  w2s[256];          // -2*w              1 KB
    __shared__ float2 a2[1024];          // (A2 r0, A2 r1)    8 KB
    __shared__ float  sred[8 * 1024];    // 8 planes          32 KB
    __shared__ float  wsum0[16], wsum1[16];

    if (t < 256) {
        hrow[t] = make_float2(Ehd[((size_t)row0 << 8) + t],
                              Ehd[((size_t)(row0 + 1) << 8) + t]);
        w2s[t] = -2.0f * wsc[t];
    }
    __syncthreads();

    // ---- phase 1 ----
    {
        int jq = t & 255, hq = t >> 8;
        const float* pB = EhpT + ((size_t)((b << 8) + (hq << 6))) * NP + (jq << 2);
        float a00 = 0, a01 = 0, a02 = 0, a03 = 0;
        float a10 = 0, a11 = 0, a12 = 0, a13 = 0;
        for (int hh = 0; hh < 64; ++hh) {
            int h = (hq << 6) + hh;
            float2 hv = hrow[h];             // LDS broadcast
            float wv = w2s[h];
            float4 p = *(const float4*)(pB + (size_t)hh * NP);
            a00 = fmaf(wv, __builtin_amdgcn_rcpf(fmaf(hv.x, p.x, 1.f)), a00);
            a01 = fmaf(wv, __builtin_amdgcn_rcpf(fmaf(hv.x, p.y, 1.f)), a01);
            a02 = fmaf(wv, __builtin_amdgcn_rcpf(fmaf(hv.x, p.z, 1.f)), a02);
            a03 = fmaf(wv, __builtin_amdgcn_rcpf(fmaf(hv.x, p.w, 1.f)), a03);
            a10 = fmaf(wv, __builtin_amdgcn_rcpf(fmaf(hv.y, p.x, 1.f)), a10);
            a11 = fmaf(wv, __builtin_amdgcn_rcpf(fmaf(hv.y, p.y, 1.f)), a11);
            a12 = fmaf(wv, __builtin_amdgcn_rcpf(fmaf(hv.y, p.z, 1.f)), a12);
            a13 = fmaf(wv, __builtin_amdgcn_rcpf(fmaf(hv.y, p.w, 1.f)), a13);
        }
        int base = (hq << 8) + jq;
        sred[0 * 1024 + base] = a00;  sred[1 * 1024 + base] = a01;
        sred[2 * 1024 + base] = a02;  sred[3 * 1024 + base] = a03;
        sred[4 * 1024 + base] = a10;  sred[5 * 1024 + base] = a11;
        sred[6 * 1024 + base] = a12;  sred[7 * 1024 + base] = a13;
    }
    __syncthreads();

    // ---- phase 2: j = t, both rows ----
    {
        int jq2 = t >> 2, c = t & 3;
        const float* p0 = sred + c * 1024 + jq2;
        const float* p1 = sred + (4 + c) * 1024 + jq2;
        float sc0 = (p0[0] + p0[256]) + (p0[512] + p0[768]);
        float sc1 = (p1[0] + p1[256]) + (p1[512] + p1[768]);
        const float L2E = 1.4426950408889634f;
        float e0 = __builtin_amdgcn_exp2f(sc0 * L2E);
        float e1 = __builtin_amdgcn_exp2f(sc1 * L2E);
        float s0 = e0, s1 = e1;
#pragma unroll
        for (int off = 32; off > 0; off >>= 1) {
            s0 += __shfl_xor(s0, off, 64);
            s1 += __shfl_xor(s1, off, 64);
        }
        if ((t & 63) == 0) { wsum0[t >> 6] = s0; wsum1[t >> 6] = s1; }
        __syncthreads();
        float tot0 = 0.f, tot1 = 0.f;
#pragma unroll
        for (int w = 0; w < 16; ++w) { tot0 += wsum0[w]; tot1 += wsum1[w]; }
        float sn0 = -2.0f * __builtin_amdgcn_rcpf(tot0);
        float sn1 = -2.0f * __builtin_amdgcn_rcpf(tot1);
        a2[t] = make_float2(e0 * sn0, e1 * sn1);
    }
    __syncthreads();                     // a2 ready; sred reads done

    // ---- phase 3 ----
    {
        int oq = t & 63, jg = t >> 6;
        int o0 = oq << 2;
        float4 fd0 = *(const float4*)(Efd + ((size_t)row0 << 8) + o0);
        float4 fd1 = *(const float4*)(Efd + ((size_t)(row0 + 1) << 8) + o0);
        const float* fpB = Efp + ((size_t)(b * NP + (jg << 6)) << 8) + o0;
        float b00 = 0, b01 = 0, b02 = 0, b03 = 0;
        float b10 = 0, b11 = 0, b12 = 0, b13 = 0;
        for (int jj = 0; jj < 64; ++jj) {
            float4 f = *(const float4*)(fpB + ((size_t)jj << 8));
            float2 av = a2[(jg << 6) + jj];   // LDS broadcast
            b00 = fmaf(av.x, __builtin_amdgcn_rcpf(fmaf(fd0.x, f.x, 1.f)), b00);
            b01 = fmaf(av.x, __builtin_amdgcn_rcpf(fmaf(fd0.y, f.y, 1.f)), b01);
            b02 = fmaf(av.x, __builtin_amdgcn_rcpf(fmaf(fd0.z, f.z, 1.f)), b02);
            b03 = fmaf(av.x, __builtin_amdgcn_rcpf(fmaf(fd0.w, f.w, 1.f)), b03);
            b10 = fmaf(av.y, __builtin_amdgcn_rcpf(fmaf(fd1.x, f.x, 1.f)), b10);
            b11 = fmaf(av.y, __builtin_amdgcn_rcpf(fmaf(fd1.y, f.y, 1.f)), b11);
            b12 = fmaf(av.y, __builtin_amdgcn_rcpf(fmaf(fd1.z, f.z, 1.f)), b12);
            b13 = fmaf(av.y, __builtin_amdgcn_rcpf(fmaf(fd1.w, f.w, 1.f)), b13);
        }
        __syncthreads();                 // sred free for reuse
        int base = (jg << 6) + oq;
        sred[0 * 1024 + base] = b00;  sred[1 * 1024 + base] = b01;
        sred[2 * 1024 + base] = b02;  sred[3 * 1024 + base] = b03;
        sred[4 * 1024 + base] = b10;  sred[5 * 1024 + base] = b11;
        sred[6 * 1024 + base] = b12;  sred[7 * 1024 + base] = b13;
    }
    __syncthreads();

    if (t < 512) {
        int r = t >> 8, o = t & 255;
        int oq2 = o >> 2, c2 = o & 3;
        const float* pk = sred + (r * 4 + c2) * 1024 + oq2;
        float s = 0.f;
#pragma unroll
        for (int g = 0; g < 16; ++g) s += pk[g << 6];
        part[((size_t)((b << 6) + (pair << 1) + r) << 8) + o] = s;
    }
}

// K3: out[b][o] = 64 + sum over 64 i-rows. grid = 8. part layout [b][i][o].
__global__ __launch_bounds__(256) void k_reduce(
    const float* __restrict__ part, float* __restrict__ out) {
    int b = blockIdx.x, t = threadIdx.x;
    float s = 64.0f;   // sum_i sum_j A_ij * 1
#pragma unroll 8
    for (int i = 0; i < 64; ++i)
        s += part[((size_t)((b << 6) + i) << 8) + t];
    out[(b << 8) + t] = s;
}

extern "C" void kernel_launch(void* const* d_in, const int* in_sizes, int n_in,
                              void* d_out, int out_size, void* d_ws, size_t ws_size,
                              hipStream_t stream) {
    const float* Xd  = (const float*)d_in[0];
    const float* Xp  = (const float*)d_in[1];
    const float* Wd  = (const float*)d_in[2];
    const float* Wp  = (const float*)d_in[3];
    const float* Wa  = (const float*)d_in[4];
    const float* Wb  = (const float*)d_in[5];
    const float* wsc = (const float*)d_in[6];
    float* out = (float*)d_out;

    float* ws = (float*)d_ws;
    float* Ehd  = ws;                       // 131072 f
    float* Efd  = Ehd + NB * ND * HID;      // 131072 f
    float* EhpT = Efd + NB * ND * OUTD;     // 2097152 f  ([b][h][j])
    float* Efp  = EhpT + NB * NP * HID;     // 2097152 f
    float* stage = Efp + NB * NP * OUTD;    // staging region (bf16)
    ushort* Xpbf = (ushort*)stage;          // 2 MB
    ushort* Xdbf = Xpbf + NB * NP * KDIM;
    ushort* WdT  = Xdbf + 65536;
    ushort* WaT  = WdT + 32768;
    ushort* WpT  = WaT + 32768;
    ushort* WbT  = WpT + 32768;
    float* part  = stage;                   // overlay: stage dead after k_proj_mfma

    k_cast     <<<1216, 256, 0, stream>>>(Xd, Xp, Wd, Wa, Wp, Wb,
                                          Xdbf, Xpbf, WdT, WaT, WpT, WbT);
    k_proj_mfma<<<1088, 256, 0, stream>>>(Xpbf, Xdbf, WdT, WaT, WpT, WbT,
                                          Ehd, Efd, EhpT, Efp);
    k_fused    <<<256, 1024, 0, stream>>>(Ehd, EhpT, Efd, Efp, wsc, part);
    k_reduce   <<<NB, 256, 0, stream>>>(part, out);
}

// Round 17
// 63.412 us; speedup vs baseline: 1.1729x; 1.0361x over previous
//
#include <hip/hip_runtime.h>

#define NB   8
#define ND   64
#define NP   1024
#define KDIM 128
#define HID  256
#define OUTD 256
#define CSC  2.885390081777927f   // 2*log2(e)
#define PSTR 1048                 // sred plane stride: !=0 mod 32 -> <=2-way banks

typedef __attribute__((ext_vector_type(8))) short  bf16x8;
typedef __attribute__((ext_vector_type(4))) float  f32x4;

// E-trick: sigma = rcp(fma(Ed,Ep,1)); tanh = 1-2*sigma. EhpT transposed.
// R17: k_fused had ~18us VALU-idle (1-deep load pipeline vs ~200cy latency).
// Fix: explicit 2-deep rotating register prefetch in phases 1 & 3; padded
// sred planes (1048) kill the 4-way phase-2 bank conflicts.

__device__ __forceinline__ ushort f2bf(float f) {
    unsigned u = __float_as_uint(f);
    return (ushort)((u + 0x7FFFu + ((u >> 16) & 1u)) >> 16);
}

// K0: cast X -> bf16 (k-contig); W -> bf16 TRANSPOSED (WT[n][k]).
__global__ __launch_bounds__(256) void k_cast(
    const float* __restrict__ Xd, const float* __restrict__ Xp,
    const float* __restrict__ Wd, const float* __restrict__ Wa,
    const float* __restrict__ Wp, const float* __restrict__ Wb,
    ushort* __restrict__ Xdbf, ushort* __restrict__ Xpbf,
    ushort* __restrict__ WdT, ushort* __restrict__ WaT,
    ushort* __restrict__ WpT, ushort* __restrict__ WbT) {
    int blk = blockIdx.x, t = threadIdx.x;
    if (blk < 1024) {
        size_t i = ((size_t)blk << 10) + ((size_t)t << 2);
        float4 v = *(const float4*)(Xp + i);
        ushort4 o; o.x = f2bf(v.x); o.y = f2bf(v.y); o.z = f2bf(v.z); o.w = f2bf(v.w);
        *(ushort4*)(Xpbf + i) = o;
    } else if (blk < 1088) {
        size_t i = ((size_t)(blk - 1024) << 10) + ((size_t)t << 2);
        float4 v = *(const float4*)(Xd + i);
        ushort4 o; o.x = f2bf(v.x); o.y = f2bf(v.y); o.z = f2bf(v.z); o.w = f2bf(v.w);
        *(ushort4*)(Xdbf + i) = o;
    } else {
        int r = blk - 1088, mat = r >> 5;
        const float* W = (mat == 0) ? Wd : (mat == 1) ? Wa : (mat == 2) ? Wp : Wb;
        ushort* WT = (mat == 0) ? WdT : (mat == 1) ? WaT : (mat == 2) ? WpT : WbT;
        int o0 = ((r & 31) << 10) + (t << 2);
        int n = o0 >> 7, k0 = o0 & 127;
        ushort4 o;
        o.x = f2bf(W[(k0 + 0) * HID + n]);
        o.y = f2bf(W[(k0 + 1) * HID + n]);
        o.z = f2bf(W[(k0 + 2) * HID + n]);
        o.w = f2bf(W[(k0 + 3) * HID + n]);
        *(ushort4*)(WT + o0) = o;
    }
}

// K1: MFMA projection + fused exp2 (verified absmax 0.0625).
__global__ __launch_bounds__(256) void k_proj_mfma(
    const ushort* __restrict__ Xpbf, const ushort* __restrict__ Xdbf,
    const ushort* __restrict__ WdT, const ushort* __restrict__ WaT,
    const ushort* __restrict__ WpT, const ushort* __restrict__ WbT,
    float* __restrict__ Ehd, float* __restrict__ Efd,
    float* __restrict__ EhpT, float* __restrict__ Efp) {
    int blk = blockIdx.x, t = threadIdx.x;
    const ushort *A, *B;
    float* out; size_t obase; int ostride, am0, bn0;
    if (blk < 512) {
        int mt = blk >> 2, nt = blk & 3;
        A = Xpbf; am0 = mt * 64; B = WbT; bn0 = nt * 64;
        out = Efp; obase = (size_t)am0 * HID + bn0; ostride = HID;
    } else if (blk < 1024) {
        int r = blk - 512, b = r >> 6, rr = r & 63;
        int mt = rr >> 4, nt = rr & 15;
        A = WpT; am0 = mt * 64;
        B = Xpbf + (size_t)b * NP * KDIM; bn0 = nt * 64;
        out = EhpT; obase = ((size_t)(b * 256 + am0)) * NP + bn0; ostride = NP;
    } else if (blk < 1056) {
        int r = blk - 1024; int mt = r >> 2, nt = r & 3;
        A = Xdbf; am0 = mt * 64; B = WdT; bn0 = nt * 64;
        out = Ehd; obase = (size_t)am0 * HID + bn0; ostride = HID;
    } else {
        int r = blk - 1056; int mt = r >> 2, nt = r & 3;
        A = Xdbf; am0 = mt * 64; B = WaT; bn0 = nt * 64;
        out = Efd; obase = (size_t)am0 * HID + bn0; ostride = HID;
    }
    int l = t & 63, w = t >> 6;
    int wm = (w >> 1) << 5, wn = (w & 1) << 5;
    int lr = l & 15, lk = (l >> 4) << 3;
    const ushort* Ab = A + (size_t)(am0 + wm + lr) * KDIM + lk;
    const ushort* Bb = B + (size_t)(bn0 + wn + lr) * KDIM + lk;

    bf16x8 af[2][4], bfr[2][4];
#pragma unroll
    for (int f = 0; f < 2; ++f)
#pragma unroll
        for (int ks = 0; ks < 4; ++ks) {
            af[f][ks]  = *(const bf16x8*)(Ab + (size_t)(f << 4) * KDIM + (ks << 5));
            bfr[f][ks] = *(const bf16x8*)(Bb + (size_t)(f << 4) * KDIM + (ks << 5));
        }

    f32x4 acc[2][2];
#pragma unroll
    for (int mf = 0; mf < 2; ++mf)
#pragma unroll
        for (int nf = 0; nf < 2; ++nf) acc[mf][nf] = (f32x4){0.f, 0.f, 0.f, 0.f};
#pragma unroll
    for (int ks = 0; ks < 4; ++ks)
#pragma unroll
        for (int mf = 0; mf < 2; ++mf)
#pragma unroll
            for (int nf = 0; nf < 2; ++nf)
                acc[mf][nf] = __builtin_amdgcn_mfma_f32_16x16x32_bf16(
                    af[mf][ks], bfr[nf][ks], acc[mf][nf], 0, 0, 0);

#pragma unroll
    for (int mf = 0; mf < 2; ++mf)
#pragma unroll
        for (int nf = 0; nf < 2; ++nf)
#pragma unroll
            for (int r = 0; r < 4; ++r) {
                int m = wm + (mf << 4) + ((l >> 4) << 2) + r;
                int n = wn + (nf << 4) + (l & 15);
                out[obase + (size_t)m * ostride + n] =
                    __builtin_amdgcn_exp2f(acc[mf][nf][r] * CSC);
            }
}

// K2: FUSED scores+softmax+facc, 2 i-rows per block, grid 256, 1024 thr.
// Phases 1 & 3 use 2-deep rotating register prefetch (pc/pn/pf).
__global__ __launch_bounds__(1024) void k_fused(
    const float* __restrict__ Ehd, const float* __restrict__ EhpT,
    const float* __restrict__ Efd, const float* __restrict__ Efp,
    const float* __restrict__ wsc, float* __restrict__ part) {
    int blk = blockIdx.x;
    int b = blk & 7, pair = blk >> 3;
    int row0 = b * ND + pair * 2;
    int t = threadIdx.x;

    __shared__ float2 hrow[256];
    __shared__ float  w2s[256];
    __shared__ float2 a2[1024];
    __shared__ float  sred[8 * PSTR];
    __shared__ float  wsum0[16], wsum1[16];

    if (t < 256) {
        hrow[t] = make_float2(Ehd[((size_t)row0 << 8) + t],
                              Ehd[((size_t)(row0 + 1) << 8) + t]);
        w2s[t] = -2.0f * wsc[t];
    }
    __syncthreads();

    // ---- phase 1: 2-deep prefetch over 64 h-rows ----
    {
        int jq = t & 255, hq = t >> 8;
        const float* pB = EhpT + ((size_t)((b << 8) + (hq << 6))) * NP + (jq << 2);
        float a00 = 0, a01 = 0, a02 = 0, a03 = 0;
        float a10 = 0, a11 = 0, a12 = 0, a13 = 0;
        float4 pc = *(const float4*)(pB);
        float4 pn = *(const float4*)(pB + NP);
#pragma unroll
        for (int hh = 0; hh < 64; ++hh) {
            float4 pf = pc;
            if (hh + 2 < 64) pf = *(const float4*)(pB + (size_t)(hh + 2) * NP);
            int h = (hq << 6) + hh;
            float2 hv = hrow[h];
            float wv = w2s[h];
            a00 = fmaf(wv, __builtin_amdgcn_rcpf(fmaf(hv.x, pc.x, 1.f)), a00);
            a01 = fmaf(wv, __builtin_amdgcn_rcpf(fmaf(hv.x, pc.y, 1.f)), a01);
            a02 = fmaf(wv, __builtin_amdgcn_rcpf(fmaf(hv.x, pc.z, 1.f)), a02);
            a03 = fmaf(wv, __builtin_amdgcn_rcpf(fmaf(hv.x, pc.w, 1.f)), a03);
            a10 = fmaf(wv, __builtin_amdgcn_rcpf(fmaf(hv.y, pc.x, 1.f)), a10);
            a11 = fmaf(wv, __builtin_amdgcn_rcpf(fmaf(hv.y, pc.y, 1.f)), a11);
            a12 = fmaf(wv, __builtin_amdgcn_rcpf(fmaf(hv.y, pc.z, 1.f)), a12);
            a13 = fmaf(wv, __builtin_amdgcn_rcpf(fmaf(hv.y, pc.w, 1.f)), a13);
            pc = pn; pn = pf;
        }
        int base = (hq << 8) + jq;
        sred[0 * PSTR + base] = a00;  sred[1 * PSTR + base] = a01;
        sred[2 * PSTR + base] = a02;  sred[3 * PSTR + base] = a03;
        sred[4 * PSTR + base] = a10;  sred[5 * PSTR + base] = a11;
        sred[6 * PSTR + base] = a12;  sred[7 * PSTR + base] = a13;
    }
    __syncthreads();

    // ---- phase 2: j = t, both rows ----
    {
        int jq2 = t >> 2, c = t & 3;
        const float* p0 = sred + c * PSTR + jq2;
        const float* p1 = sred + (4 + c) * PSTR + jq2;
        float sc0 = (p0[0] + p0[256]) + (p0[512] + p0[768]);
        float sc1 = (p1[0] + p1[256]) + (p1[512] + p1[768]);
        const float L2E = 1.4426950408889634f;
        float e0 = __builtin_amdgcn_exp2f(sc0 * L2E);
        float e1 = __builtin_amdgcn_exp2f(sc1 * L2E);
        float s0 = e0, s1 = e1;
#pragma unroll
        for (int off = 32; off > 0; off >>= 1) {
            s0 += __shfl_xor(s0, off, 64);
            s1 += __shfl_xor(s1, off, 64);
        }
        if ((t & 63) == 0) { wsum0[t >> 6] = s0; wsum1[t >> 6] = s1; }
        __syncthreads();
        float tot0 = 0.f, tot1 = 0.f;
#pragma unroll
        for (int w = 0; w < 16; ++w) { tot0 += wsum0[w]; tot1 += wsum1[w]; }
        float sn0 = -2.0f * __builtin_amdgcn_rcpf(tot0);
        float sn1 = -2.0f * __builtin_amdgcn_rcpf(tot1);
        a2[t] = make_float2(e0 * sn0, e1 * sn1);
    }
    __syncthreads();

    // ---- phase 3: 2-deep prefetch over 64 j-rows ----
    {
        int oq = t & 63, jg = t >> 6;
        int o0 = oq << 2;
        float4 fd0 = *(const float4*)(Efd + ((size_t)row0 << 8) + o0);
        float4 fd1 = *(const float4*)(Efd + ((size_t)(row0 + 1) << 8) + o0);
        const float* fpB = Efp + ((size_t)(b * NP + (jg << 6)) << 8) + o0;
        float b00 = 0, b01 = 0, b02 = 0, b03 = 0;
        float b10 = 0, b11 = 0, b12 = 0, b13 = 0;
        float4 fc = *(const float4*)(fpB);
        float4 fn = *(const float4*)(fpB + 256);
#pragma unroll
        for (int jj = 0; jj < 64; ++jj) {
            float4 ff = fc;
            if (jj + 2 < 64) ff = *(const float4*)(fpB + ((size_t)(jj + 2) << 8));
            float2 av = a2[(jg << 6) + jj];
            b00 = fmaf(av.x, __builtin_amdgcn_rcpf(fmaf(fd0.x, fc.x, 1.f)), b00);
            b01 = fmaf(av.x, __builtin_amdgcn_rcpf(fmaf(fd0.y, fc.y, 1.f)), b01);
            b02 = fmaf(av.x, __builtin_amdgcn_rcpf(fmaf(fd0.z, fc.z, 1.f)), b02);
            b03 = fmaf(av.x, __builtin_amdgcn_rcpf(fmaf(fd0.w, fc.w, 1.f)), b03);
            b10 = fmaf(av.y, __builtin_amdgcn_rcpf(fmaf(fd1.x, fc.x, 1.f)), b10);
            b11 = fmaf(av.y, __builtin_amdgcn_rcpf(fmaf(fd1.y, fc.y, 1.f)), b11);
            b12 = fmaf(av.y, __builtin_amdgcn_rcpf(fmaf(fd1.z, fc.z, 1.f)), b12);
            b13 = fmaf(av.y, __builtin_amdgcn_rcpf(fmaf(fd1.w, fc.w, 1.f)), b13);
            fc = fn; fn = ff;
        }
        __syncthreads();                 // sred free for reuse
        int base = (jg << 6) + oq;
        sred[0 * PSTR + base] = b00;  sred[1 * PSTR + base] = b01;
        sred[2 * PSTR + base] = b02;  sred[3 * PSTR + base] = b03;
        sred[4 * PSTR + base] = b10;  sred[5 * PSTR + base] = b11;
        sred[6 * PSTR + base] = b12;  sred[7 * PSTR + base] = b13;
    }
    __syncthreads();

    if (t < 512) {
        int r = t >> 8, o = t & 255;
        int oq2 = o >> 2, c2 = o & 3;
        const float* pk = sred + (r * 4 + c2) * PSTR + oq2;
        float s = 0.f;
#pragma unroll
        for (int g = 0; g < 16; ++g) s += pk[g << 6];
        part[((size_t)((b << 6) + (pair << 1) + r) << 8) + o] = s;
    }
}

// K3: out[b][o] = 64 + sum over 64 i-rows. grid = 8. part layout [b][i][o].
__global__ __launch_bounds__(256) void k_reduce(
    const float* __restrict__ part, float* __restrict__ out) {
    int b = blockIdx.x, t = threadIdx.x;
    float s = 64.0f;
#pragma unroll 8
    for (int i = 0; i < 64; ++i)
        s += part[((size_t)((b << 6) + i) << 8) + t];
    out[(b << 8) + t] = s;
}

extern "C" void kernel_launch(void* const* d_in, const int* in_sizes, int n_in,
                              void* d_out, int out_size, void* d_ws, size_t ws_size,
                              hipStream_t stream) {
    const float* Xd  = (const float*)d_in[0];
    const float* Xp  = (const float*)d_in[1];
    const float* Wd  = (const float*)d_in[2];
    const float* Wp  = (const float*)d_in[3];
    const float* Wa  = (const float*)d_in[4];
    const float* Wb  = (const float*)d_in[5];
    const float* wsc = (const float*)d_in[6];
    float* out = (float*)d_out;

    float* ws = (float*)d_ws;
    float* Ehd  = ws;
    float* Efd  = Ehd + NB * ND * HID;
    float* EhpT = Efd + NB * ND * OUTD;
    float* Efp  = EhpT + NB * NP * HID;
    float* stage = Efp + NB * NP * OUTD;
    ushort* Xpbf = (ushort*)stage;
    ushort* Xdbf = Xpbf + NB * NP * KDIM;
    ushort* WdT  = Xdbf + 65536;
    ushort* WaT  = WdT + 32768;
    ushort* WpT  = WaT + 32768;
    ushort* WbT  = WpT + 32768;
    float* part  = stage;

    k_cast     <<<1216, 256, 0, stream>>>(Xd, Xp, Wd, Wa, Wp, Wb,
                                          Xdbf, Xpbf, WdT, WaT, WpT, WbT);
    k_proj_mfma<<<1088, 256, 0, stream>>>(Xpbf, Xdbf, WdT, WaT, WpT, WbT,
                                          Ehd, Efd, EhpT, Efp);
    k_fused    <<<256, 1024, 0, stream>>>(Ehd, EhpT, Efd, Efp, wsc, part);
    k_reduce   <<<NB, 256, 0, stream>>>(part, out);
}